// Round 4
// baseline (1527.248 us; speedup 1.0000x reference)
//
#include <hip/hip_runtime.h>

#define N_NODES 50000
#define N_EDGES 800000
#define PDIM 3
#define FDIM 64
#define MDIM 32
#define NLAYERS 2
#define EINDIM 129
#define H1 258          // 2*EIN
#define CH 128          // 4*M
#define NH 128          // 2*F
#define XDIM 67         // P+F
#define K1P 136         // e_in LDS k-stride (128 + 8 pad)
#define H1T 288         // padded h rows (18 tiles of 16)
#define W1T_K 136       // w1t k-dim (128 + 8 pad)
#define MLSTR 40        // ml LDS row stride (bf16)

typedef __attribute__((ext_vector_type(8))) short short8;
typedef __attribute__((ext_vector_type(4))) float f32x4;

__device__ __forceinline__ float fsilu(float x) {
  return x / (1.0f + __expf(-x));
}

__device__ __forceinline__ unsigned short f2bf(float f) {
  union { float f; unsigned u; } v; v.f = f;
  unsigned r = v.u + 0x7FFF + ((v.u >> 16) & 1);  // RNE
  return (unsigned short)(r >> 16);
}

__device__ __forceinline__ float bf2f(unsigned short u) {
  union { unsigned u; float f; } v; v.u = ((unsigned)u) << 16;
  return v.f;
}

__device__ __forceinline__ unsigned cvt_pk(float lo, float hi) {
  unsigned r;
  asm("v_cvt_pk_bf16_f32 %0, %1, %2" : "=v"(r) : "v"(lo), "v"(hi));
  return r;
}

// Assemble a B-fragment (8 bf16, k-contig) from two packed C-layout tiles.
// PA0/PA1 = lo tile (rows kg'*4+{0..3} packed as pairs), PB0/PB1 = hi tile.
// Target lane (kg,ln15) word w <- P[tile = hi?B:A][w&1] from lane ((kg&1)*2+(w>>1))*16+ln15.
__device__ __forceinline__ short8 assembleB(unsigned PA0, unsigned PA1,
                                            unsigned PB0, unsigned PB1,
                                            int addrA, int addrB, bool hi) {
  union { unsigned u[4]; short8 s; } o;
  unsigned a0 = __builtin_amdgcn_ds_bpermute(addrA, (int)PA0);
  unsigned b0 = __builtin_amdgcn_ds_bpermute(addrA, (int)PB0);
  o.u[0] = hi ? b0 : a0;
  unsigned a1 = __builtin_amdgcn_ds_bpermute(addrA, (int)PA1);
  unsigned b1 = __builtin_amdgcn_ds_bpermute(addrA, (int)PB1);
  o.u[1] = hi ? b1 : a1;
  unsigned a2 = __builtin_amdgcn_ds_bpermute(addrB, (int)PA0);
  unsigned b2 = __builtin_amdgcn_ds_bpermute(addrB, (int)PB0);
  o.u[2] = hi ? b2 : a2;
  unsigned a3 = __builtin_amdgcn_ds_bpermute(addrB, (int)PA1);
  unsigned b3 = __builtin_amdgcn_ds_bpermute(addrB, (int)PB1);
  o.u[3] = hi ? b3 : a3;
  return o.s;
}

// ---- CSR build ----
__global__ void count_kernel(const int* __restrict__ ei, int* __restrict__ cnt) {
  int e = blockIdx.x * 256 + threadIdx.x;
  if (e < N_EDGES) atomicAdd(&cnt[ei[N_EDGES + e]], 1);
}

__global__ __launch_bounds__(1024)
void scan_kernel(const int* __restrict__ cnt, int* __restrict__ csr, int* __restrict__ cursor) {
  __shared__ int partial[1024];
  const int tid = threadIdx.x;
  const int CHUNK = 49;
  int base = tid * CHUNK;
  int s = 0;
  for (int i = 0; i < CHUNK; ++i) {
    int idx = base + i;
    if (idx < N_NODES) s += cnt[idx];
  }
  partial[tid] = s;
  __syncthreads();
  for (int off = 1; off < 1024; off <<= 1) {
    int v = (tid >= off) ? partial[tid - off] : 0;
    __syncthreads();
    partial[tid] += v;
    __syncthreads();
  }
  int run = partial[tid] - s;
  for (int i = 0; i < CHUNK; ++i) {
    int idx = base + i;
    if (idx < N_NODES) {
      csr[idx] = run;
      cursor[idx] = run;
      run += cnt[idx];
    }
  }
  if (tid == 1023) csr[N_NODES] = run;
}

__global__ void rank_kernel(const int* __restrict__ ei, int* __restrict__ cursor,
                            int* __restrict__ pos) {
  int e = blockIdx.x * 256 + threadIdx.x;
  if (e < N_EDGES) pos[e] = atomicAdd(&cursor[ei[N_EDGES + e]], 1);
}

// ---- weight prep ----
// w1t [L][288 j][136 k]; w2t [L][32 n][288 k]; cw1t [L][128 n][32 k];
// b1p [L][288] f32; wrp [L][288] f32 (eW1 row 128, zero-padded)
__global__ void prep_weights(const float* __restrict__ eW1, const float* __restrict__ eW2,
                             const float* __restrict__ cW1, const float* __restrict__ eb1,
                             unsigned short* __restrict__ w1t, unsigned short* __restrict__ w2t,
                             unsigned short* __restrict__ cw1t,
                             float* __restrict__ b1p, float* __restrict__ wrp) {
  int idx = blockIdx.x * 256 + threadIdx.x;
  const int n1 = NLAYERS * H1T * W1T_K;
  const int n2 = NLAYERS * MDIM * H1T;
  const int n3 = NLAYERS * CH * MDIM;
  const int n4 = NLAYERS * H1T;
  if (idx < n1) {
    int k = idx % W1T_K;
    int rest = idx / W1T_K;
    int j = rest % H1T;
    int l = rest / H1T;
    float v = (k < 128 && j < H1) ? eW1[(l * EINDIM + k) * H1 + j] : 0.0f;
    w1t[idx] = f2bf(v);
  } else if (idx < n1 + n2) {
    int t = idx - n1;
    int k = t % H1T;
    int rest = t / H1T;
    int n = rest % MDIM;
    int l = rest / MDIM;
    float v = (k < H1) ? eW2[(l * H1 + k) * MDIM + n] : 0.0f;
    w2t[t] = f2bf(v);
  } else if (idx < n1 + n2 + n3) {
    int t = idx - n1 - n2;
    int k = t % MDIM;
    int rest = t / MDIM;
    int n = rest % CH;
    int l = rest / CH;
    cw1t[t] = f2bf(cW1[(l * MDIM + k) * CH + n]);
  } else if (idx < n1 + n2 + n3 + n4) {
    int t = idx - n1 - n2 - n3;
    int j = t % H1T;
    int l = t / H1T;
    b1p[t] = (j < H1) ? eb1[l * H1 + j] : 0.0f;
  } else if (idx < n1 + n2 + n3 + 2 * n4) {
    int t = idx - n1 - n2 - n3 - n4;
    int j = t % H1T;
    int l = t / H1T;
    wrp[t] = (j < H1) ? eW1[((size_t)l * EINDIM + 128) * H1 + j] : 0.0f;
  }
}

// convert X features to bf16 [N][64]
__global__ void convert_x(const float* __restrict__ X, unsigned short* __restrict__ Xb) {
  int idx = blockIdx.x * 256 + threadIdx.x;
  if (idx >= N_NODES * 8) return;
  int n = idx >> 3, c = idx & 7;
  const float* src = X + n * XDIM + PDIM + c * 8;
  short8 v;
  #pragma unroll
  for (int i = 0; i < 8; ++i) v[i] = (short)f2bf(src[i]);
  *(short8*)&Xb[n * 64 + c * 8] = v;
}

__global__ __launch_bounds__(256, 3)
void edge_mfma_kernel(const float* __restrict__ X,
                      const unsigned short* __restrict__ Xb,
                      const int* __restrict__ ei, const int* __restrict__ pos,
                      const unsigned short* __restrict__ w1t,
                      const float* __restrict__ b1p, const float* __restrict__ wrp,
                      const unsigned short* __restrict__ w2t, const float* __restrict__ eb2,
                      const unsigned short* __restrict__ cw1t, const float* __restrict__ cb1,
                      const float* __restrict__ cW2, const float* __restrict__ cb2,
                      const float* __restrict__ cscale,
                      unsigned short* __restrict__ ms, float* __restrict__ mh4,
                      int layer)
{
  __shared__ unsigned short einLds[64 * K1P];   // 17.4 KB
  __shared__ unsigned short ml[64 * MLSTR];     // 5.1 KB
  __shared__ float rel3[64 * 3];
  __shared__ float distLds[64];
  __shared__ float cwLds[64];
  __shared__ int sdS[64], sdD[64], pse[64];

  const int tid = threadIdx.x;
  const int lane = tid & 63;
  const int wid = tid >> 6;      // edge-tile 0..3
  const int ln15 = lane & 15;
  const int kg = lane >> 4;
  const int e0 = blockIdx.x * 64;

  if (tid < 64) {
    int s = ei[e0 + tid];
    int d = ei[N_EDGES + e0 + tid];
    sdS[tid] = s; sdD[tid] = d;
    pse[tid] = pos[e0 + tid];
    float rx = X[s * XDIM + 0] - X[d * XDIM + 0];
    float ry = X[s * XDIM + 1] - X[d * XDIM + 1];
    float rz = X[s * XDIM + 2] - X[d * XDIM + 2];
    rel3[tid * 3 + 0] = rx;
    rel3[tid * 3 + 1] = ry;
    rel3[tid * 3 + 2] = rz;
    distLds[tid] = rx * rx + ry * ry + rz * rz;
  }
  __syncthreads();

  // stage e_in bf16 [64 e][128 k] = [featsB[dst] | featsB[src]]
  #pragma unroll
  for (int it = 0; it < 4; ++it) {
    int idx = tid + it * 256;
    int e = idx >> 4, c = idx & 15;
    int node = (c < 8) ? sdD[e] : sdS[e];
    short8 v = *(const short8*)&Xb[node * 64 + (c & 7) * 8];
    *(short8*)&einLds[e * K1P + c * 8] = v;
  }
  __syncthreads();

  // hoisted B-fragments of e_inT (col = edge, reused across all 18 j-tiles)
  short8 einB[4];
  #pragma unroll
  for (int ks = 0; ks < 4; ++ks)
    einB[ks] = *(const short8*)&einLds[(wid * 16 + ln15) * K1P + ks * 32 + kg * 8];
  const float distv = distLds[wid * 16 + ln15];

  const int addrA = ((lane & 16) << 3) + (ln15 << 2);  // src lane (kg&1)*2 .. *4B
  const int addrB = addrA + 64;
  const bool hi = (lane & 32) != 0;

  // ---- phase B: hT[288][64] = silu(W1tile . e_inT + b1 + wr*dist), packed bf16 pairs ----
  const unsigned short* W1T = w1t + layer * H1T * W1T_K;
  const float* B1P = b1p + layer * H1T;
  const float* WRP = wrp + layer * H1T;
  unsigned P[36];
  #pragma unroll
  for (int jt = 0; jt < 18; ++jt) {
    f32x4 b4 = *(const f32x4*)&B1P[jt * 16 + kg * 4];
    f32x4 w4 = *(const f32x4*)&WRP[jt * 16 + kg * 4];
    f32x4 acc;
    #pragma unroll
    for (int r = 0; r < 4; ++r) acc[r] = fmaf(distv, w4[r], b4[r]);
    #pragma unroll
    for (int ks = 0; ks < 4; ++ks) {
      short8 a = *(const short8*)&W1T[(jt * 16 + ln15) * W1T_K + ks * 32 + kg * 8];
      acc = __builtin_amdgcn_mfma_f32_16x16x32_bf16(a, einB[ks], acc, 0, 0, 0);
    }
    float s0 = fsilu(acc[0]), s1 = fsilu(acc[1]);
    float s2 = fsilu(acc[2]), s3 = fsilu(acc[3]);
    P[jt * 2 + 0] = cvt_pk(s0, s1);
    P[jt * 2 + 1] = cvt_pk(s2, s3);
  }

  // ---- phase C: mT[32][64] = silu(W2T . hT + b2) ----
  const unsigned short* W2T = w2t + layer * MDIM * H1T;
  const float* B2 = eb2 + layer * MDIM;
  f32x4 mac0 = *(const f32x4*)&B2[kg * 4];
  f32x4 mac1 = *(const f32x4*)&B2[16 + kg * 4];
  #pragma unroll
  for (int ks = 0; ks < 9; ++ks) {
    short8 bfrag = assembleB(P[4 * ks + 0], P[4 * ks + 1], P[4 * ks + 2], P[4 * ks + 3],
                             addrA, addrB, hi);
    short8 a0 = *(const short8*)&W2T[(ln15) * H1T + ks * 32 + kg * 8];
    short8 a1 = *(const short8*)&W2T[(16 + ln15) * H1T + ks * 32 + kg * 8];
    mac0 = __builtin_amdgcn_mfma_f32_16x16x32_bf16(a0, bfrag, mac0, 0, 0, 0);
    mac1 = __builtin_amdgcn_mfma_f32_16x16x32_bf16(a1, bfrag, mac1, 0, 0, 0);
  }
  unsigned PM[4];
  {
    float v0 = fsilu(mac0[0]), v1 = fsilu(mac0[1]), v2 = fsilu(mac0[2]), v3 = fsilu(mac0[3]);
    float v4 = fsilu(mac1[0]), v5 = fsilu(mac1[1]), v6 = fsilu(mac1[2]), v7 = fsilu(mac1[3]);
    PM[0] = cvt_pk(v0, v1);
    PM[1] = cvt_pk(v2, v3);
    PM[2] = cvt_pk(v4, v5);
    PM[3] = cvt_pk(v6, v7);
  }
  // stash m rows to ml (per-edge 32 bf16) for the coalesced global write
  {
    const int erow = wid * 16 + ln15;
    *(unsigned*)&ml[erow * MLSTR + kg * 4 + 0] = PM[0];
    *(unsigned*)&ml[erow * MLSTR + kg * 4 + 2] = PM[1];
    *(unsigned*)&ml[erow * MLSTR + 16 + kg * 4 + 0] = PM[2];
    *(unsigned*)&ml[erow * MLSTR + 16 + kg * 4 + 2] = PM[3];
  }

  // ---- phase D: c1T[128][64] = cW1T . mT + cb1; cw = tanh(sum silu(c1)*cW2 + cb2) ----
  short8 mB = assembleB(PM[0], PM[1], PM[2], PM[3], addrA, addrB, hi);
  const unsigned short* CW1T = cw1t + layer * CH * MDIM;
  const float* CB1 = cb1 + layer * CH;
  const float* CW2v = cW2 + layer * CH;
  float psum = 0.0f;
  #pragma unroll
  for (int nt = 0; nt < 8; ++nt) {
    f32x4 cacc = *(const f32x4*)&CB1[nt * 16 + kg * 4];
    short8 a = *(const short8*)&CW1T[(nt * 16 + ln15) * MDIM + kg * 8];
    cacc = __builtin_amdgcn_mfma_f32_16x16x32_bf16(a, mB, cacc, 0, 0, 0);
    f32x4 w2 = *(const f32x4*)&CW2v[nt * 16 + kg * 4];
    #pragma unroll
    for (int r = 0; r < 4; ++r) psum += fsilu(cacc[r]) * w2[r];
  }
  psum += __shfl_xor(psum, 16, 64);
  psum += __shfl_xor(psum, 32, 64);
  if (lane < 16) cwLds[wid * 16 + ln15] = psum;
  __syncthreads();

  // coalesced m_ij write (64B/edge, CSR-sorted position)
  {
    int e = tid >> 2, seg = tid & 3;
    short8 v = *(const short8*)&ml[e * MLSTR + seg * 8];
    *(short8*)&ms[(size_t)pse[e] * MDIM + seg * 8] = v;
  }
  if (tid < 64) {
    float cw = tanhf(cwLds[tid] + cb2[layer]);
    float fac = cw * cscale[layer] / fmaxf(sqrtf(distLds[tid]), 1e-8f);
    *(float4*)&mh4[(size_t)pse[tid] * 4] =
        make_float4(fac * rel3[tid * 3 + 0], fac * rel3[tid * 3 + 1],
                    fac * rel3[tid * 3 + 2], 0.0f);
  }
}

__global__ __launch_bounds__(256)
void gather_node_kernel(const float* __restrict__ Xin,
                        const unsigned short* __restrict__ ms,
                        const float* __restrict__ mh4,
                        const int* __restrict__ csr,
                        const float* __restrict__ nW1, const float* __restrict__ nb1,
                        const float* __restrict__ nW2, const float* __restrict__ nb2,
                        float* __restrict__ Xout, unsigned short* __restrict__ Xb,
                        int writeXb, int layer)
{
  __shared__ float nin[4][97];
  __shared__ float hn[4][NH + 1];
  __shared__ float mhs[4][3];
  const int tid = threadIdx.x;
  const int w = tid >> 6;
  const int lane = tid & 63;
  const int n = blockIdx.x * 4 + w;

  const int off = csr[n];
  const int end = csr[n + 1];

  {
    const int col = lane & 31;
    const int hh = lane >> 5;
    float s = 0.0f;
    for (int r = off + hh; r < end; r += 2)
      s += bf2f(ms[(size_t)r * MDIM + col]);
    s += __shfl_xor(s, 32, 64);
    if (hh == 0) nin[w][FDIM + col] = s;
  }
  {
    const int mc = lane & 3;
    const int mr = lane >> 2;
    float t = 0.0f;
    for (int r = off + mr; r < end; r += 16)
      t += mh4[(size_t)r * 4 + mc];
    t += __shfl_xor(t, 4, 64);
    t += __shfl_xor(t, 8, 64);
    t += __shfl_xor(t, 16, 64);
    t += __shfl_xor(t, 32, 64);
    if (lane < 3) mhs[w][lane] = t;
  }
  nin[w][lane] = Xin[n * XDIM + PDIM + lane];
  __syncthreads();

  const float* W1 = nW1 + layer * (FDIM + MDIM) * NH;
  const float* B1 = nb1 + layer * NH;
  float a0 = B1[lane];
  float a1 = B1[lane + 64];
  #pragma unroll 4
  for (int k = 0; k < FDIM + MDIM; ++k) {
    float v = nin[w][k];
    a0 = fmaf(v, W1[k * NH + lane], a0);
    a1 = fmaf(v, W1[k * NH + lane + 64], a1);
  }
  hn[w][lane] = fsilu(a0);
  hn[w][lane + 64] = fsilu(a1);
  __syncthreads();

  const float* W2 = nW2 + layer * NH * FDIM;
  float acc = nb2[layer * FDIM + lane];
  #pragma unroll 4
  for (int k = 0; k < NH; ++k)
    acc = fmaf(hn[w][k], W2[k * FDIM + lane], acc);

  float feat = Xin[n * XDIM + PDIM + lane];
  float outv = feat + acc;
  Xout[n * XDIM + PDIM + lane] = outv;
  if (writeXb) Xb[n * 64 + lane] = f2bf(outv);
  if (lane < PDIM)
    Xout[n * XDIM + lane] = Xin[n * XDIM + lane] + mhs[w][lane];
}

extern "C" void kernel_launch(void* const* d_in, const int* in_sizes, int n_in,
                              void* d_out, int out_size, void* d_ws, size_t ws_size,
                              hipStream_t stream) {
  const float* x      = (const float*)d_in[0];
  const int*   ei     = (const int*)d_in[1];
  const float* eW1    = (const float*)d_in[2];
  const float* eb1    = (const float*)d_in[3];
  const float* eW2    = (const float*)d_in[4];
  const float* eb2    = (const float*)d_in[5];
  const float* cW1    = (const float*)d_in[6];
  const float* cb1    = (const float*)d_in[7];
  const float* cW2    = (const float*)d_in[8];
  const float* cb2    = (const float*)d_in[9];
  const float* nW1    = (const float*)d_in[10];
  const float* nb1    = (const float*)d_in[11];
  const float* nW2    = (const float*)d_in[12];
  const float* nb2    = (const float*)d_in[13];
  const float* cscale = (const float*)d_in[14];

  float* ws     = (float*)d_ws;
  float* X1     = ws;                                   // N*67 f32
  float* mh4    = X1 + N_NODES * XDIM;                  // E*4 f32
  int*   csr    = (int*)(mh4 + (size_t)N_EDGES * 4);    // N+4
  int*   cursor = csr + N_NODES + 4;                    // N
  int*   cnt    = cursor + N_NODES;                     // N
  int*   pos    = cnt + N_NODES;                        // E
  unsigned short* w1t  = (unsigned short*)(pos + N_EDGES);
  unsigned short* w2t  = w1t + NLAYERS * H1T * W1T_K;
  unsigned short* cw1t = w2t + NLAYERS * MDIM * H1T;
  float* b1p = (float*)(cw1t + NLAYERS * CH * MDIM);
  float* wrp = b1p + NLAYERS * H1T;
  unsigned short* Xb = (unsigned short*)(wrp + NLAYERS * H1T);  // N*64 bf16
  unsigned short* ms = Xb + (size_t)N_NODES * 64;               // E*32 bf16

  hipMemsetAsync(cnt, 0, N_NODES * sizeof(int), stream);
  count_kernel<<<(N_EDGES + 255) / 256, 256, 0, stream>>>(ei, cnt);
  scan_kernel<<<1, 1024, 0, stream>>>(cnt, csr, cursor);
  rank_kernel<<<(N_EDGES + 255) / 256, 256, 0, stream>>>(ei, cursor, pos);
  {
    const int total = NLAYERS * (H1T * W1T_K + MDIM * H1T + CH * MDIM + 2 * H1T);
    prep_weights<<<(total + 255) / 256, 256, 0, stream>>>(eW1, eW2, cW1, eb1,
                                                          w1t, w2t, cw1t, b1p, wrp);
  }
  convert_x<<<(N_NODES * 8 + 255) / 256, 256, 0, stream>>>(x, Xb);

  for (int l = 0; l < NLAYERS; ++l) {
    const float* Xin = (l == 0) ? x : X1;
    float* Xout = (l == 0) ? X1 : (float*)d_out;
    edge_mfma_kernel<<<N_EDGES / 64, 256, 0, stream>>>(
        Xin, Xb, ei, pos, w1t, b1p, wrp, w2t, eb2, cw1t, cb1, cW2, cb2, cscale,
        ms, mh4, l);
    gather_node_kernel<<<N_NODES / 4, 256, 0, stream>>>(
        Xin, ms, mh4, csr, nW1, nb1, nW2, nb2, Xout, Xb, (l == 0) ? 1 : 0, l);
  }
}

// Round 5
// 1090.758 us; speedup vs baseline: 1.4002x; 1.4002x over previous
//
#include <hip/hip_runtime.h>

#define N_NODES 50000
#define N_EDGES 800000
#define PDIM 3
#define FDIM 64
#define MDIM 32
#define NLAYERS 2
#define EINDIM 129
#define H1 258          // 2*EIN
#define CH 128          // 4*M
#define NH 128          // 2*F
#define XDIM 67         // P+F
#define H1T 288         // padded h dim (18 tiles of 16)
#define HSTR 296        // hLds j-stride (bf16)
#define W1T_K 136       // w1t k-dim (128 + 8 pad)
#define MLSTR 40        // ml LDS row stride (bf16)

typedef __attribute__((ext_vector_type(8))) short short8;
typedef __attribute__((ext_vector_type(4))) float f32x4;

__device__ __forceinline__ float fsilu(float x) {
  return x / (1.0f + __expf(-x));
}

__device__ __forceinline__ unsigned short f2bf(float f) {
  union { float f; unsigned u; } v; v.f = f;
  unsigned r = v.u + 0x7FFF + ((v.u >> 16) & 1);  // RNE
  return (unsigned short)(r >> 16);
}

__device__ __forceinline__ float bf2f(unsigned short u) {
  union { unsigned u; float f; } v; v.u = ((unsigned)u) << 16;
  return v.f;
}

__device__ __forceinline__ unsigned cvt_pk(float lo, float hi) {
  unsigned r;
  asm("v_cvt_pk_bf16_f32 %0, %1, %2" : "=v"(r) : "v"(lo), "v"(hi));
  return r;
}

// ---- CSR build ----
__global__ void count_kernel(const int* __restrict__ ei, int* __restrict__ cnt) {
  int e = blockIdx.x * 256 + threadIdx.x;
  if (e < N_EDGES) atomicAdd(&cnt[ei[N_EDGES + e]], 1);
}

__global__ __launch_bounds__(1024)
void scan_kernel(const int* __restrict__ cnt, int* __restrict__ csr, int* __restrict__ cursor) {
  __shared__ int partial[1024];
  const int tid = threadIdx.x;
  const int CHUNK = 49;
  int base = tid * CHUNK;
  int s = 0;
  for (int i = 0; i < CHUNK; ++i) {
    int idx = base + i;
    if (idx < N_NODES) s += cnt[idx];
  }
  partial[tid] = s;
  __syncthreads();
  for (int off = 1; off < 1024; off <<= 1) {
    int v = (tid >= off) ? partial[tid - off] : 0;
    __syncthreads();
    partial[tid] += v;
    __syncthreads();
  }
  int run = partial[tid] - s;
  for (int i = 0; i < CHUNK; ++i) {
    int idx = base + i;
    if (idx < N_NODES) {
      csr[idx] = run;
      cursor[idx] = run;
      run += cnt[idx];
    }
  }
  if (tid == 1023) csr[N_NODES] = run;
}

__global__ void rank_kernel(const int* __restrict__ ei, int* __restrict__ cursor,
                            int* __restrict__ pos) {
  int e = blockIdx.x * 256 + threadIdx.x;
  if (e < N_EDGES) pos[e] = atomicAdd(&cursor[ei[N_EDGES + e]], 1);
}

// ---- weight prep ----
__global__ void prep_weights(const float* __restrict__ eW1, const float* __restrict__ eW2,
                             const float* __restrict__ cW1, const float* __restrict__ eb1,
                             unsigned short* __restrict__ w1t, unsigned short* __restrict__ w2t,
                             unsigned short* __restrict__ cw1t,
                             float* __restrict__ b1p, float* __restrict__ wrp) {
  int idx = blockIdx.x * 256 + threadIdx.x;
  const int n1 = NLAYERS * H1T * W1T_K;
  const int n2 = NLAYERS * MDIM * H1T;
  const int n3 = NLAYERS * CH * MDIM;
  const int n4 = NLAYERS * H1T;
  if (idx < n1) {
    int k = idx % W1T_K;
    int rest = idx / W1T_K;
    int j = rest % H1T;
    int l = rest / H1T;
    float v = (k < 128 && j < H1) ? eW1[(l * EINDIM + k) * H1 + j] : 0.0f;
    w1t[idx] = f2bf(v);
  } else if (idx < n1 + n2) {
    int t = idx - n1;
    int k = t % H1T;
    int rest = t / H1T;
    int n = rest % MDIM;
    int l = rest / MDIM;
    float v = (k < H1) ? eW2[(l * H1 + k) * MDIM + n] : 0.0f;
    w2t[t] = f2bf(v);
  } else if (idx < n1 + n2 + n3) {
    int t = idx - n1 - n2;
    int k = t % MDIM;
    int rest = t / MDIM;
    int n = rest % CH;
    int l = rest / CH;
    cw1t[t] = f2bf(cW1[(l * MDIM + k) * CH + n]);
  } else if (idx < n1 + n2 + n3 + n4) {
    int t = idx - n1 - n2 - n3;
    int j = t % H1T;
    int l = t / H1T;
    b1p[t] = (j < H1) ? eb1[l * H1 + j] : 0.0f;
  } else if (idx < n1 + n2 + n3 + 2 * n4) {
    int t = idx - n1 - n2 - n3 - n4;
    int j = t % H1T;
    int l = t / H1T;
    wrp[t] = (j < H1) ? eW1[((size_t)l * EINDIM + 128) * H1 + j] : 0.0f;
  }
}

// convert X features to bf16 [N][64]
__global__ void convert_x(const float* __restrict__ X, unsigned short* __restrict__ Xb) {
  int idx = blockIdx.x * 256 + threadIdx.x;
  if (idx >= N_NODES * 8) return;
  int n = idx >> 3, c = idx & 7;
  const float* src = X + n * XDIM + PDIM + c * 8;
  short8 v;
  #pragma unroll
  for (int i = 0; i < 8; ++i) v[i] = (short)f2bf(src[i]);
  *(short8*)&Xb[n * 64 + c * 8] = v;
}

__global__ __launch_bounds__(256, 3)
void edge_mfma_kernel(const float* __restrict__ X,
                      const unsigned short* __restrict__ Xb,
                      const int* __restrict__ ei, const int* __restrict__ pos,
                      const unsigned short* __restrict__ w1t,
                      const float* __restrict__ b1p, const float* __restrict__ wrp,
                      const unsigned short* __restrict__ w2t, const float* __restrict__ eb2,
                      const unsigned short* __restrict__ cw1t, const float* __restrict__ cb1,
                      const float* __restrict__ cW2, const float* __restrict__ cb2,
                      const float* __restrict__ cscale,
                      unsigned short* __restrict__ ms, float* __restrict__ mh4,
                      int layer)
{
  __shared__ unsigned short hLds[64 * HSTR];   // 37.9 KB, [e][j] j-contig
  __shared__ unsigned short ml[64 * MLSTR];    // 5.1 KB,  [e][n] n-contig
  __shared__ float rel3[64 * 3];
  __shared__ float distLds[64];
  __shared__ float cwLds[64];
  __shared__ int sdS[64], sdD[64], pse[64];

  const int tid = threadIdx.x;
  const int lane = tid & 63;
  const int wid = tid >> 6;
  const int ln15 = lane & 15;
  const int kg = lane >> 4;
  const int e0 = blockIdx.x * 64;

  if (tid < 64) {
    int s = ei[e0 + tid];
    int d = ei[N_EDGES + e0 + tid];
    sdS[tid] = s; sdD[tid] = d;
    pse[tid] = pos[e0 + tid];
    float rx = X[s * XDIM + 0] - X[d * XDIM + 0];
    float ry = X[s * XDIM + 1] - X[d * XDIM + 1];
    float rz = X[s * XDIM + 2] - X[d * XDIM + 2];
    rel3[tid * 3 + 0] = rx;
    rel3[tid * 3 + 1] = ry;
    rel3[tid * 3 + 2] = rz;
    distLds[tid] = rx * rx + ry * ry + rz * rz;
  }
  __syncthreads();

  // B-fragments of e_inT for ALL 4 edge-tiles, direct from global Xb.
  // B-frag: lane ln15 = col = edge-in-tile, kg*8+i = k. k<64 -> dst, else src.
  short8 einB[4][4];
  float distE[4];
  #pragma unroll
  for (int et = 0; et < 4; ++et) {
    int e = et * 16 + ln15;
    int nd = sdD[e], nsr = sdS[e];
    distE[et] = distLds[e];
    #pragma unroll
    for (int ks = 0; ks < 4; ++ks) {
      int node = (ks < 2) ? nd : nsr;
      einB[et][ks] = *(const short8*)&Xb[node * 64 + (ks & 1) * 32 + kg * 8];
    }
  }

  // ---- phase B: hT tiles = W1tile . e_inT (+ b1 + wr*dist), write h[e][j] ----
  const unsigned short* W1T = w1t + layer * H1T * W1T_K;
  const float* B1P = b1p + layer * H1T;
  const float* WRP = wrp + layer * H1T;
  for (int jt = wid; jt < 18; jt += 4) {
    f32x4 b4 = *(const f32x4*)&B1P[jt * 16 + kg * 4];
    f32x4 w4 = *(const f32x4*)&WRP[jt * 16 + kg * 4];
    short8 a[4];
    #pragma unroll
    for (int ks = 0; ks < 4; ++ks)
      a[ks] = *(const short8*)&W1T[(jt * 16 + ln15) * W1T_K + ks * 32 + kg * 8];
    #pragma unroll
    for (int et = 0; et < 4; ++et) {
      f32x4 acc;
      #pragma unroll
      for (int r = 0; r < 4; ++r) acc[r] = fmaf(distE[et], w4[r], b4[r]);
      #pragma unroll
      for (int ks = 0; ks < 4; ++ks)
        acc = __builtin_amdgcn_mfma_f32_16x16x32_bf16(a[ks], einB[et][ks], acc, 0, 0, 0);
      // lane holds j = jt*16 + kg*4 + {0..3} for edge e = et*16 + ln15
      uint2 uu;
      uu.x = cvt_pk(fsilu(acc[0]), fsilu(acc[1]));
      uu.y = cvt_pk(fsilu(acc[2]), fsilu(acc[3]));
      *(uint2*)&hLds[(et * 16 + ln15) * HSTR + jt * 16 + kg * 4] = uu;
    }
  }
  __syncthreads();

  // ---- phase C: m[64e][32n] = silu(h @ W2T + b2); wave wid = edge-tile ----
  const unsigned short* W2T = w2t + layer * MDIM * H1T;
  const float* B2 = eb2 + layer * MDIM;
  {
    float b20 = B2[ln15], b21 = B2[16 + ln15];
    f32x4 mac0 = {b20, b20, b20, b20};
    f32x4 mac1 = {b21, b21, b21, b21};
    #pragma unroll
    for (int ks = 0; ks < 9; ++ks) {
      short8 ah = *(const short8*)&hLds[(wid * 16 + ln15) * HSTR + ks * 32 + kg * 8];
      short8 w0 = *(const short8*)&W2T[ln15 * H1T + ks * 32 + kg * 8];
      short8 w1 = *(const short8*)&W2T[(16 + ln15) * H1T + ks * 32 + kg * 8];
      mac0 = __builtin_amdgcn_mfma_f32_16x16x32_bf16(ah, w0, mac0, 0, 0, 0);
      mac1 = __builtin_amdgcn_mfma_f32_16x16x32_bf16(ah, w1, mac1, 0, 0, 0);
    }
    // lane: col n = ln15 (+16), rows e = wid*16 + kg*4 + r
    #pragma unroll
    for (int r = 0; r < 4; ++r) {
      int e = wid * 16 + kg * 4 + r;
      float v0 = fsilu(mac0[r]), v1 = fsilu(mac1[r]);
      ml[e * MLSTR + ln15] = (unsigned short)cvt_pk(v0, v0);
      ml[e * MLSTR + 16 + ln15] = (unsigned short)cvt_pk(v1, v1);
    }
  }
  __syncthreads();

  // ---- phase D: cw = tanh(sum_n silu(m @ cW1 + cb1)*cW2 + cb2) ----
  const unsigned short* CW1T = cw1t + layer * CH * MDIM;
  const float* CB1 = cb1 + layer * CH;
  const float* CW2v = cW2 + layer * CH;
  {
    short8 am = *(const short8*)&ml[(wid * 16 + ln15) * MLSTR + kg * 8];
    float psum[4] = {0.f, 0.f, 0.f, 0.f};
    #pragma unroll
    for (int nt = 0; nt < 8; ++nt) {
      float cb = CB1[nt * 16 + ln15];
      f32x4 cacc = {cb, cb, cb, cb};
      short8 bc = *(const short8*)&CW1T[(nt * 16 + ln15) * MDIM + kg * 8];
      cacc = __builtin_amdgcn_mfma_f32_16x16x32_bf16(am, bc, cacc, 0, 0, 0);
      float w2v = CW2v[nt * 16 + ln15];
      #pragma unroll
      for (int r = 0; r < 4; ++r) psum[r] += fsilu(cacc[r]) * w2v;
    }
    #pragma unroll
    for (int off = 1; off < 16; off <<= 1) {
      #pragma unroll
      for (int r = 0; r < 4; ++r) psum[r] += __shfl_xor(psum[r], off, 64);
    }
    if (ln15 == 0) {
      #pragma unroll
      for (int r = 0; r < 4; ++r) cwLds[wid * 16 + kg * 4 + r] = psum[r];
    }
  }
  __syncthreads();

  // coalesced m_ij write (64B/edge, CSR-sorted position)
  {
    int e = tid >> 2, seg = tid & 3;
    short8 v = *(const short8*)&ml[e * MLSTR + seg * 8];
    *(short8*)&ms[(size_t)pse[e] * MDIM + seg * 8] = v;
  }
  if (tid < 64) {
    float cw = tanhf(cwLds[tid] + cb2[layer]);
    float fac = cw * cscale[layer] / fmaxf(sqrtf(distLds[tid]), 1e-8f);
    *(float4*)&mh4[(size_t)pse[tid] * 4] =
        make_float4(fac * rel3[tid * 3 + 0], fac * rel3[tid * 3 + 1],
                    fac * rel3[tid * 3 + 2], 0.0f);
  }
}

__global__ __launch_bounds__(256)
void gather_node_kernel(const float* __restrict__ Xin,
                        const unsigned short* __restrict__ ms,
                        const float* __restrict__ mh4,
                        const int* __restrict__ csr,
                        const float* __restrict__ nW1, const float* __restrict__ nb1,
                        const float* __restrict__ nW2, const float* __restrict__ nb2,
                        float* __restrict__ Xout, unsigned short* __restrict__ Xb,
                        int writeXb, int layer)
{
  __shared__ float nin[4][97];
  __shared__ float hn[4][NH + 1];
  __shared__ float mhs[4][3];
  const int tid = threadIdx.x;
  const int w = tid >> 6;
  const int lane = tid & 63;
  const int n = blockIdx.x * 4 + w;

  const int off = csr[n];
  const int end = csr[n + 1];

  {
    const int col = lane & 31;
    const int hh = lane >> 5;
    float s = 0.0f;
    for (int r = off + hh; r < end; r += 2)
      s += bf2f(ms[(size_t)r * MDIM + col]);
    s += __shfl_xor(s, 32, 64);
    if (hh == 0) nin[w][FDIM + col] = s;
  }
  {
    const int mc = lane & 3;
    const int mr = lane >> 2;
    float t = 0.0f;
    for (int r = off + mr; r < end; r += 16)
      t += mh4[(size_t)r * 4 + mc];
    t += __shfl_xor(t, 4, 64);
    t += __shfl_xor(t, 8, 64);
    t += __shfl_xor(t, 16, 64);
    t += __shfl_xor(t, 32, 64);
    if (lane < 3) mhs[w][lane] = t;
  }
  nin[w][lane] = Xin[n * XDIM + PDIM + lane];
  __syncthreads();

  const float* W1 = nW1 + layer * (FDIM + MDIM) * NH;
  const float* B1 = nb1 + layer * NH;
  float a0 = B1[lane];
  float a1 = B1[lane + 64];
  #pragma unroll 4
  for (int k = 0; k < FDIM + MDIM; ++k) {
    float v = nin[w][k];
    a0 = fmaf(v, W1[k * NH + lane], a0);
    a1 = fmaf(v, W1[k * NH + lane + 64], a1);
  }
  hn[w][lane] = fsilu(a0);
  hn[w][lane + 64] = fsilu(a1);
  __syncthreads();

  const float* W2 = nW2 + layer * NH * FDIM;
  float acc = nb2[layer * FDIM + lane];
  #pragma unroll 4
  for (int k = 0; k < NH; ++k)
    acc = fmaf(hn[w][k], W2[k * FDIM + lane], acc);

  float feat = Xin[n * XDIM + PDIM + lane];
  float outv = feat + acc;
  Xout[n * XDIM + PDIM + lane] = outv;
  if (writeXb) Xb[n * 64 + lane] = f2bf(outv);
  if (lane < PDIM)
    Xout[n * XDIM + lane] = Xin[n * XDIM + lane] + mhs[w][lane];
}

extern "C" void kernel_launch(void* const* d_in, const int* in_sizes, int n_in,
                              void* d_out, int out_size, void* d_ws, size_t ws_size,
                              hipStream_t stream) {
  const float* x      = (const float*)d_in[0];
  const int*   ei     = (const int*)d_in[1];
  const float* eW1    = (const float*)d_in[2];
  const float* eb1    = (const float*)d_in[3];
  const float* eW2    = (const float*)d_in[4];
  const float* eb2    = (const float*)d_in[5];
  const float* cW1    = (const float*)d_in[6];
  const float* cb1    = (const float*)d_in[7];
  const float* cW2    = (const float*)d_in[8];
  const float* cb2    = (const float*)d_in[9];
  const float* nW1    = (const float*)d_in[10];
  const float* nb1    = (const float*)d_in[11];
  const float* nW2    = (const float*)d_in[12];
  const float* nb2    = (const float*)d_in[13];
  const float* cscale = (const float*)d_in[14];

  float* ws     = (float*)d_ws;
  float* X1     = ws;                                   // N*67 f32
  float* mh4    = X1 + N_NODES * XDIM;                  // E*4 f32
  int*   csr    = (int*)(mh4 + (size_t)N_EDGES * 4);    // N+4
  int*   cursor = csr + N_NODES + 4;                    // N
  int*   cnt    = cursor + N_NODES;                     // N
  int*   pos    = cnt + N_NODES;                        // E
  unsigned short* w1t  = (unsigned short*)(pos + N_EDGES);
  unsigned short* w2t  = w1t + NLAYERS * H1T * W1T_K;
  unsigned short* cw1t = w2t + NLAYERS * MDIM * H1T;
  float* b1p = (float*)(cw1t + NLAYERS * CH * MDIM);
  float* wrp = b1p + NLAYERS * H1T;
  unsigned short* Xb = (unsigned short*)(wrp + NLAYERS * H1T);  // N*64 bf16
  unsigned short* ms = Xb + (size_t)N_NODES * 64;               // E*32 bf16

  hipMemsetAsync(cnt, 0, N_NODES * sizeof(int), stream);
  count_kernel<<<(N_EDGES + 255) / 256, 256, 0, stream>>>(ei, cnt);
  scan_kernel<<<1, 1024, 0, stream>>>(cnt, csr, cursor);
  rank_kernel<<<(N_EDGES + 255) / 256, 256, 0, stream>>>(ei, cursor, pos);
  {
    const int total = NLAYERS * (H1T * W1T_K + MDIM * H1T + CH * MDIM + 2 * H1T);
    prep_weights<<<(total + 255) / 256, 256, 0, stream>>>(eW1, eW2, cW1, eb1,
                                                          w1t, w2t, cw1t, b1p, wrp);
  }
  convert_x<<<(N_NODES * 8 + 255) / 256, 256, 0, stream>>>(x, Xb);

  for (int l = 0; l < NLAYERS; ++l) {
    const float* Xin = (l == 0) ? x : X1;
    float* Xout = (l == 0) ? X1 : (float*)d_out;
    edge_mfma_kernel<<<N_EDGES / 64, 256, 0, stream>>>(
        Xin, Xb, ei, pos, w1t, b1p, wrp, w2t, eb2, cw1t, cb1, cW2, cb2, cscale,
        ms, mh4, l);
    gather_node_kernel<<<N_NODES / 4, 256, 0, stream>>>(
        Xin, ms, mh4, csr, nW1, nb1, nW2, nb2, Xout, Xb, (l == 0) ? 1 : 0, l);
  }
}

// Round 6
// 1025.889 us; speedup vs baseline: 1.4887x; 1.0632x over previous
//
#include <hip/hip_runtime.h>

#define N_NODES 50000
#define N_EDGES 800000
#define PDIM 3
#define FDIM 64
#define MDIM 32
#define NLAYERS 2
#define EINDIM 129
#define H1 258          // 2*EIN
#define CH 128          // 4*M
#define NH 128          // 2*F
#define XDIM 67         // P+F
#define H1T 288         // padded h dim (18 tiles of 16)
#define HSTR 296        // hLds j-stride (bf16)
#define W1T_K 136       // w1t k-dim (128 + 8 pad)
#define MLSTR 40        // ml LDS row stride (bf16)

typedef __attribute__((ext_vector_type(8))) short short8;
typedef __attribute__((ext_vector_type(4))) float f32x4;

#define LOG2E 1.4426950408889634f

// fast silu: x * rcp(1 + 2^(-x*log2e)) — v_exp + v_rcp + 3 full-rate ops
// (avoids the ~9-op IEEE div sequence the compiler emits for '/')
__device__ __forceinline__ float fsilu(float x) {
  float e = __builtin_amdgcn_exp2f(-x * LOG2E);
  return x * __builtin_amdgcn_rcpf(1.0f + e);
}

// fast tanh: (E-1)*rcp(E+1), E = 2^(2x*log2e), clamped to avoid inf*0
__device__ __forceinline__ float ftanh(float x) {
  float xc = fminf(fmaxf(x, -15.0f), 15.0f);
  float E = __builtin_amdgcn_exp2f(2.0f * LOG2E * xc);
  return (E - 1.0f) * __builtin_amdgcn_rcpf(E + 1.0f);
}

__device__ __forceinline__ unsigned short f2bf(float f) {
  union { float f; unsigned u; } v; v.f = f;
  unsigned r = v.u + 0x7FFF + ((v.u >> 16) & 1);  // RNE
  return (unsigned short)(r >> 16);
}

__device__ __forceinline__ float bf2f(unsigned short u) {
  union { unsigned u; float f; } v; v.u = ((unsigned)u) << 16;
  return v.f;
}

__device__ __forceinline__ unsigned cvt_pk(float lo, float hi) {
  unsigned r;
  asm("v_cvt_pk_bf16_f32 %0, %1, %2" : "=v"(r) : "v"(lo), "v"(hi));
  return r;
}

// ---- CSR build ----
__global__ void count_kernel(const int* __restrict__ ei, int* __restrict__ cnt) {
  int e = blockIdx.x * 256 + threadIdx.x;
  if (e < N_EDGES) atomicAdd(&cnt[ei[N_EDGES + e]], 1);
}

__global__ __launch_bounds__(1024)
void scan_kernel(const int* __restrict__ cnt, int* __restrict__ csr, int* __restrict__ cursor) {
  __shared__ int partial[1024];
  const int tid = threadIdx.x;
  const int CHUNK = 49;
  int base = tid * CHUNK;
  int s = 0;
  for (int i = 0; i < CHUNK; ++i) {
    int idx = base + i;
    if (idx < N_NODES) s += cnt[idx];
  }
  partial[tid] = s;
  __syncthreads();
  for (int off = 1; off < 1024; off <<= 1) {
    int v = (tid >= off) ? partial[tid - off] : 0;
    __syncthreads();
    partial[tid] += v;
    __syncthreads();
  }
  int run = partial[tid] - s;
  for (int i = 0; i < CHUNK; ++i) {
    int idx = base + i;
    if (idx < N_NODES) {
      csr[idx] = run;
      cursor[idx] = run;
      run += cnt[idx];
    }
  }
  if (tid == 1023) csr[N_NODES] = run;
}

__global__ void rank_kernel(const int* __restrict__ ei, int* __restrict__ cursor,
                            int* __restrict__ pos) {
  int e = blockIdx.x * 256 + threadIdx.x;
  if (e < N_EDGES) pos[e] = atomicAdd(&cursor[ei[N_EDGES + e]], 1);
}

// ---- weight prep ----
__global__ void prep_weights(const float* __restrict__ eW1, const float* __restrict__ eW2,
                             const float* __restrict__ cW1, const float* __restrict__ eb1,
                             unsigned short* __restrict__ w1t, unsigned short* __restrict__ w2t,
                             unsigned short* __restrict__ cw1t,
                             float* __restrict__ b1p, float* __restrict__ wrp) {
  int idx = blockIdx.x * 256 + threadIdx.x;
  const int n1 = NLAYERS * H1T * W1T_K;
  const int n2 = NLAYERS * MDIM * H1T;
  const int n3 = NLAYERS * CH * MDIM;
  const int n4 = NLAYERS * H1T;
  if (idx < n1) {
    int k = idx % W1T_K;
    int rest = idx / W1T_K;
    int j = rest % H1T;
    int l = rest / H1T;
    float v = (k < 128 && j < H1) ? eW1[(l * EINDIM + k) * H1 + j] : 0.0f;
    w1t[idx] = f2bf(v);
  } else if (idx < n1 + n2) {
    int t = idx - n1;
    int k = t % H1T;
    int rest = t / H1T;
    int n = rest % MDIM;
    int l = rest / MDIM;
    float v = (k < H1) ? eW2[(l * H1 + k) * MDIM + n] : 0.0f;
    w2t[t] = f2bf(v);
  } else if (idx < n1 + n2 + n3) {
    int t = idx - n1 - n2;
    int k = t % MDIM;
    int rest = t / MDIM;
    int n = rest % CH;
    int l = rest / CH;
    cw1t[t] = f2bf(cW1[(l * MDIM + k) * CH + n]);
  } else if (idx < n1 + n2 + n3 + n4) {
    int t = idx - n1 - n2 - n3;
    int j = t % H1T;
    int l = t / H1T;
    b1p[t] = (j < H1) ? eb1[l * H1 + j] : 0.0f;
  } else if (idx < n1 + n2 + n3 + 2 * n4) {
    int t = idx - n1 - n2 - n3 - n4;
    int j = t % H1T;
    int l = t / H1T;
    wrp[t] = (j < H1) ? eW1[((size_t)l * EINDIM + 128) * H1 + j] : 0.0f;
  }
}

// convert X features to bf16 [N][64]
__global__ void convert_x(const float* __restrict__ X, unsigned short* __restrict__ Xb) {
  int idx = blockIdx.x * 256 + threadIdx.x;
  if (idx >= N_NODES * 8) return;
  int n = idx >> 3, c = idx & 7;
  const float* src = X + n * XDIM + PDIM + c * 8;
  short8 v;
  #pragma unroll
  for (int i = 0; i < 8; ++i) v[i] = (short)f2bf(src[i]);
  *(short8*)&Xb[n * 64 + c * 8] = v;
}

__global__ __launch_bounds__(256, 3)
void edge_mfma_kernel(const float* __restrict__ X,
                      const unsigned short* __restrict__ Xb,
                      const int* __restrict__ ei, const int* __restrict__ pos,
                      const unsigned short* __restrict__ w1t,
                      const float* __restrict__ b1p, const float* __restrict__ wrp,
                      const unsigned short* __restrict__ w2t, const float* __restrict__ eb2,
                      const unsigned short* __restrict__ cw1t, const float* __restrict__ cb1,
                      const float* __restrict__ cW2, const float* __restrict__ cb2,
                      const float* __restrict__ cscale,
                      unsigned short* __restrict__ ms, float* __restrict__ mh4,
                      int layer)
{
  __shared__ unsigned short hLds[64 * HSTR];   // 37.9 KB, [e][j] j-contig
  __shared__ unsigned short ml[64 * MLSTR];    // 5.1 KB,  [e][n] n-contig
  __shared__ float rel3[64 * 3];
  __shared__ float distLds[64];
  __shared__ float cwLds[64];
  __shared__ int sdS[64], sdD[64], pse[64];

  const int tid = threadIdx.x;
  const int lane = tid & 63;
  const int wid = tid >> 6;
  const int ln15 = lane & 15;
  const int kg = lane >> 4;
  const int e0 = blockIdx.x * 64;

  if (tid < 64) {
    int s = ei[e0 + tid];
    int d = ei[N_EDGES + e0 + tid];
    sdS[tid] = s; sdD[tid] = d;
    pse[tid] = pos[e0 + tid];
    float rx = X[s * XDIM + 0] - X[d * XDIM + 0];
    float ry = X[s * XDIM + 1] - X[d * XDIM + 1];
    float rz = X[s * XDIM + 2] - X[d * XDIM + 2];
    rel3[tid * 3 + 0] = rx;
    rel3[tid * 3 + 1] = ry;
    rel3[tid * 3 + 2] = rz;
    distLds[tid] = rx * rx + ry * ry + rz * rz;
  }
  __syncthreads();

  // B-fragments of e_inT for ALL 4 edge-tiles, direct from global Xb.
  short8 einB[4][4];
  float distE[4];
  #pragma unroll
  for (int et = 0; et < 4; ++et) {
    int e = et * 16 + ln15;
    int nd = sdD[e], nsr = sdS[e];
    distE[et] = distLds[e];
    #pragma unroll
    for (int ks = 0; ks < 4; ++ks) {
      int node = (ks < 2) ? nd : nsr;
      einB[et][ks] = *(const short8*)&Xb[node * 64 + (ks & 1) * 32 + kg * 8];
    }
  }

  // ---- phase B: hT tiles = W1tile . e_inT (+ b1 + wr*dist), write h[e][j] ----
  const unsigned short* W1T = w1t + layer * H1T * W1T_K;
  const float* B1P = b1p + layer * H1T;
  const float* WRP = wrp + layer * H1T;
  for (int jt = wid; jt < 18; jt += 4) {
    f32x4 b4 = *(const f32x4*)&B1P[jt * 16 + kg * 4];
    f32x4 w4 = *(const f32x4*)&WRP[jt * 16 + kg * 4];
    short8 a[4];
    #pragma unroll
    for (int ks = 0; ks < 4; ++ks)
      a[ks] = *(const short8*)&W1T[(jt * 16 + ln15) * W1T_K + ks * 32 + kg * 8];
    #pragma unroll
    for (int et = 0; et < 4; ++et) {
      f32x4 acc;
      #pragma unroll
      for (int r = 0; r < 4; ++r) acc[r] = fmaf(distE[et], w4[r], b4[r]);
      #pragma unroll
      for (int ks = 0; ks < 4; ++ks)
        acc = __builtin_amdgcn_mfma_f32_16x16x32_bf16(a[ks], einB[et][ks], acc, 0, 0, 0);
      uint2 uu;
      uu.x = cvt_pk(fsilu(acc[0]), fsilu(acc[1]));
      uu.y = cvt_pk(fsilu(acc[2]), fsilu(acc[3]));
      *(uint2*)&hLds[(et * 16 + ln15) * HSTR + jt * 16 + kg * 4] = uu;
    }
  }
  __syncthreads();

  // ---- phase C: m[64e][32n] = silu(h @ W2T + b2); wave wid = edge-tile ----
  const unsigned short* W2T = w2t + layer * MDIM * H1T;
  const float* B2 = eb2 + layer * MDIM;
  {
    float b20 = B2[ln15], b21 = B2[16 + ln15];
    f32x4 mac0 = {b20, b20, b20, b20};
    f32x4 mac1 = {b21, b21, b21, b21};
    #pragma unroll
    for (int ks = 0; ks < 9; ++ks) {
      short8 ah = *(const short8*)&hLds[(wid * 16 + ln15) * HSTR + ks * 32 + kg * 8];
      short8 w0 = *(const short8*)&W2T[ln15 * H1T + ks * 32 + kg * 8];
      short8 w1 = *(const short8*)&W2T[(16 + ln15) * H1T + ks * 32 + kg * 8];
      mac0 = __builtin_amdgcn_mfma_f32_16x16x32_bf16(ah, w0, mac0, 0, 0, 0);
      mac1 = __builtin_amdgcn_mfma_f32_16x16x32_bf16(ah, w1, mac1, 0, 0, 0);
    }
    #pragma unroll
    for (int r = 0; r < 4; ++r) {
      int e = wid * 16 + kg * 4 + r;
      float v0 = fsilu(mac0[r]), v1 = fsilu(mac1[r]);
      ml[e * MLSTR + ln15] = f2bf(v0);
      ml[e * MLSTR + 16 + ln15] = f2bf(v1);
    }
  }
  __syncthreads();

  // ---- phase D: cw = tanh(sum_n silu(m @ cW1 + cb1)*cW2 + cb2) ----
  const unsigned short* CW1T = cw1t + layer * CH * MDIM;
  const float* CB1 = cb1 + layer * CH;
  const float* CW2v = cW2 + layer * CH;
  {
    short8 am = *(const short8*)&ml[(wid * 16 + ln15) * MLSTR + kg * 8];
    float psum[4] = {0.f, 0.f, 0.f, 0.f};
    #pragma unroll
    for (int nt = 0; nt < 8; ++nt) {
      float cb = CB1[nt * 16 + ln15];
      f32x4 cacc = {cb, cb, cb, cb};
      short8 bc = *(const short8*)&CW1T[(nt * 16 + ln15) * MDIM + kg * 8];
      cacc = __builtin_amdgcn_mfma_f32_16x16x32_bf16(am, bc, cacc, 0, 0, 0);
      float w2v = CW2v[nt * 16 + ln15];
      #pragma unroll
      for (int r = 0; r < 4; ++r) psum[r] += fsilu(cacc[r]) * w2v;
    }
    #pragma unroll
    for (int off = 1; off < 16; off <<= 1) {
      #pragma unroll
      for (int r = 0; r < 4; ++r) psum[r] += __shfl_xor(psum[r], off, 64);
    }
    if (ln15 == 0) {
      #pragma unroll
      for (int r = 0; r < 4; ++r) cwLds[wid * 16 + kg * 4 + r] = psum[r];
    }
  }
  __syncthreads();

  // coalesced m_ij write (64B/edge, CSR-sorted position)
  {
    int e = tid >> 2, seg = tid & 3;
    short8 v = *(const short8*)&ml[e * MLSTR + seg * 8];
    *(short8*)&ms[(size_t)pse[e] * MDIM + seg * 8] = v;
  }
  if (tid < 64) {
    float cw = ftanh(cwLds[tid] + cb2[layer]);
    float fac = cw * cscale[layer] / fmaxf(sqrtf(distLds[tid]), 1e-8f);
    *(float4*)&mh4[(size_t)pse[tid] * 4] =
        make_float4(fac * rel3[tid * 3 + 0], fac * rel3[tid * 3 + 1],
                    fac * rel3[tid * 3 + 2], 0.0f);
  }
}

__global__ __launch_bounds__(256)
void gather_node_kernel(const float* __restrict__ Xin,
                        const unsigned short* __restrict__ ms,
                        const float* __restrict__ mh4,
                        const int* __restrict__ csr,
                        const float* __restrict__ nW1, const float* __restrict__ nb1,
                        const float* __restrict__ nW2, const float* __restrict__ nb2,
                        float* __restrict__ Xout, unsigned short* __restrict__ Xb,
                        int writeXb, int layer)
{
  __shared__ float nin[4][97];
  __shared__ float hn[4][NH + 1];
  __shared__ float mhs[4][3];
  const int tid = threadIdx.x;
  const int w = tid >> 6;
  const int lane = tid & 63;
  const int n = blockIdx.x * 4 + w;

  const int off = csr[n];
  const int end = csr[n + 1];

  {
    const int col = lane & 31;
    const int hh = lane >> 5;
    float s = 0.0f;
    for (int r = off + hh; r < end; r += 2)
      s += bf2f(ms[(size_t)r * MDIM + col]);
    s += __shfl_xor(s, 32, 64);
    if (hh == 0) nin[w][FDIM + col] = s;
  }
  {
    const int mc = lane & 3;
    const int mr = lane >> 2;
    float t = 0.0f;
    for (int r = off + mr; r < end; r += 16)
      t += mh4[(size_t)r * 4 + mc];
    t += __shfl_xor(t, 4, 64);
    t += __shfl_xor(t, 8, 64);
    t += __shfl_xor(t, 16, 64);
    t += __shfl_xor(t, 32, 64);
    if (lane < 3) mhs[w][lane] = t;
  }
  nin[w][lane] = Xin[n * XDIM + PDIM + lane];
  __syncthreads();

  const float* W1 = nW1 + layer * (FDIM + MDIM) * NH;
  const float* B1 = nb1 + layer * NH;
  float a0 = B1[lane];
  float a1 = B1[lane + 64];
  #pragma unroll 4
  for (int k = 0; k < FDIM + MDIM; ++k) {
    float v = nin[w][k];
    a0 = fmaf(v, W1[k * NH + lane], a0);
    a1 = fmaf(v, W1[k * NH + lane + 64], a1);
  }
  hn[w][lane] = fsilu(a0);
  hn[w][lane + 64] = fsilu(a1);
  __syncthreads();

  const float* W2 = nW2 + layer * NH * FDIM;
  float acc = nb2[layer * FDIM + lane];
  #pragma unroll 4
  for (int k = 0; k < NH; ++k)
    acc = fmaf(hn[w][k], W2[k * FDIM + lane], acc);

  float feat = Xin[n * XDIM + PDIM + lane];
  float outv = feat + acc;
  Xout[n * XDIM + PDIM + lane] = outv;
  if (writeXb) Xb[n * 64 + lane] = f2bf(outv);
  if (lane < PDIM)
    Xout[n * XDIM + lane] = Xin[n * XDIM + lane] + mhs[w][lane];
}

extern "C" void kernel_launch(void* const* d_in, const int* in_sizes, int n_in,
                              void* d_out, int out_size, void* d_ws, size_t ws_size,
                              hipStream_t stream) {
  const float* x      = (const float*)d_in[0];
  const int*   ei     = (const int*)d_in[1];
  const float* eW1    = (const float*)d_in[2];
  const float* eb1    = (const float*)d_in[3];
  const float* eW2    = (const float*)d_in[4];
  const float* eb2    = (const float*)d_in[5];
  const float* cW1    = (const float*)d_in[6];
  const float* cb1    = (const float*)d_in[7];
  const float* cW2    = (const float*)d_in[8];
  const float* cb2    = (const float*)d_in[9];
  const float* nW1    = (const float*)d_in[10];
  const float* nb1    = (const float*)d_in[11];
  const float* nW2    = (const float*)d_in[12];
  const float* nb2    = (const float*)d_in[13];
  const float* cscale = (const float*)d_in[14];

  float* ws     = (float*)d_ws;
  float* X1     = ws;                                   // N*67 f32
  float* mh4    = X1 + N_NODES * XDIM;                  // E*4 f32
  int*   csr    = (int*)(mh4 + (size_t)N_EDGES * 4);    // N+4
  int*   cursor = csr + N_NODES + 4;                    // N
  int*   cnt    = cursor + N_NODES;                     // N
  int*   pos    = cnt + N_NODES;                        // E
  unsigned short* w1t  = (unsigned short*)(pos + N_EDGES);
  unsigned short* w2t  = w1t + NLAYERS * H1T * W1T_K;
  unsigned short* cw1t = w2t + NLAYERS * MDIM * H1T;
  float* b1p = (float*)(cw1t + NLAYERS * CH * MDIM);
  float* wrp = b1p + NLAYERS * H1T;
  unsigned short* Xb = (unsigned short*)(wrp + NLAYERS * H1T);  // N*64 bf16
  unsigned short* ms = Xb + (size_t)N_NODES * 64;               // E*32 bf16

  hipMemsetAsync(cnt, 0, N_NODES * sizeof(int), stream);
  count_kernel<<<(N_EDGES + 255) / 256, 256, 0, stream>>>(ei, cnt);
  scan_kernel<<<1, 1024, 0, stream>>>(cnt, csr, cursor);
  rank_kernel<<<(N_EDGES + 255) / 256, 256, 0, stream>>>(ei, cursor, pos);
  {
    const int total = NLAYERS * (H1T * W1T_K + MDIM * H1T + CH * MDIM + 2 * H1T);
    prep_weights<<<(total + 255) / 256, 256, 0, stream>>>(eW1, eW2, cW1, eb1,
                                                          w1t, w2t, cw1t, b1p, wrp);
  }
  convert_x<<<(N_NODES * 8 + 255) / 256, 256, 0, stream>>>(x, Xb);

  for (int l = 0; l < NLAYERS; ++l) {
    const float* Xin = (l == 0) ? x : X1;
    float* Xout = (l == 0) ? X1 : (float*)d_out;
    edge_mfma_kernel<<<N_EDGES / 64, 256, 0, stream>>>(
        Xin, Xb, ei, pos, w1t, b1p, wrp, w2t, eb2, cw1t, cb1, cW2, cb2, cscale,
        ms, mh4, l);
    gather_node_kernel<<<N_NODES / 4, 256, 0, stream>>>(
        Xin, ms, mh4, csr, nW1, nb1, nW2, nb2, Xout, Xb, (l == 0) ? 1 : 0, l);
  }
}